// Round 10
// baseline (119.904 us; speedup 1.0000x reference)
//
#include <hip/hip_runtime.h>
#include <math.h>

// Problem constants (B=4, H=16, S=4096, D=64, m=256)
#define DNORM   0.35355339059327376f   // sqrt(softmax_temp) = (1/8)^0.5
#define DIAG_F  0.0625f                // 0.5 * softmax_temp
#define HLM     2.772588722239781f     // log(256)/2
#define ROWS_TOTAL   262144            // B*H*S
#define FEAT_ELEMS   67108864          // B*H*S*256
#define ROWS_PER_BLK 128
#define NBLOCKS      2048              // ROWS_TOTAL / 128
#define BLKS_PER_BH  32                // 4096 / 128
#define QPANELS      2048              // total q panels
#define QSPLIT       1024              // q-panels done in phase 1
#define OB_STRIDE    264               // fp32 words per buffered row (bank-spread)

// Wave-local LDS handoff fence (cross-lane pass through LDS without a block
// barrier): memory clobber stops compiler reordering, lgkmcnt(0) orders HW.
#define LDS_FENCE() asm volatile("s_waitcnt lgkmcnt(0)" ::: "memory")

using bf16x8 = __attribute__((ext_vector_type(8))) short;
using f32x4  = __attribute__((ext_vector_type(4))) float;

__device__ __forceinline__ unsigned short f2bf(float f) {
    unsigned int u = __builtin_bit_cast(unsigned int, f);
    u = (u + 0x7FFFu + ((u >> 16) & 1u)) >> 16;   // RNE
    return (unsigned short)u;
}

__device__ __forceinline__ bf16x8 pack8(float4 a, float4 b) {
    bf16x8 r;
    r[0] = (short)f2bf(a.x); r[1] = (short)f2bf(a.y);
    r[2] = (short)f2bf(a.z); r[3] = (short)f2bf(a.w);
    r[4] = (short)f2bf(b.x); r[5] = (short)f2bf(b.y);
    r[6] = (short)f2bf(b.z); r[7] = (short)f2bf(b.w);
    return r;
}

// ---------------------------------------------------------------------------
// Stage proj (128x64 fp32, *DNORM) into MFMA fragment order in LDS.
// ---------------------------------------------------------------------------
__device__ __forceinline__ void stage_proj(const float* __restrict__ proj,
                                           unsigned short (*F)[2][64][8], int t) {
    const float4* g = reinterpret_cast<const float4*>(proj);
#pragma unroll
    for (int i = 0; i < 8; ++i) {
        int c = t & 15;            // chunk within row (4 floats)
        int m = t >> 4;            // row within 16-row tile
        float4 v = g[t + i * 256];
        v.x *= DNORM; v.y *= DNORM; v.z *= DNORM; v.w *= DNORM;
        int h = c >> 3, dg = (c >> 1) & 3, half = c & 1;
        uint2 wv;
        wv.x = (unsigned int)f2bf(v.x) | ((unsigned int)f2bf(v.y) << 16);
        wv.y = (unsigned int)f2bf(v.z) | ((unsigned int)f2bf(v.w) << 16);
        *reinterpret_cast<uint2*>(&F[i][h][dg * 16 + m][half * 4]) = wv;
    }
}

// ---------------------------------------------------------------------------
// Direct-from-global data fragments + in-register diag (round-9 verified).
// ---------------------------------------------------------------------------
__device__ __forceinline__ void load_data_frags(const float* __restrict__ base,
                                                int l, int w,
                                                bf16x8 fd[2][2], float diag[2]) {
#pragma unroll
    for (int r = 0; r < 2; ++r) {
        const float* rp = base + ((w * 2 + r) * 16 + (l & 15)) * 64 + (l >> 4) * 8;
        float4 a0 = *reinterpret_cast<const float4*>(rp);
        float4 b0 = *reinterpret_cast<const float4*>(rp + 4);
        float4 a1 = *reinterpret_cast<const float4*>(rp + 32);
        float4 b1 = *reinterpret_cast<const float4*>(rp + 36);
        fd[r][0] = pack8(a0, b0);
        fd[r][1] = pack8(a1, b1);
        float ss = a0.x*a0.x + a0.y*a0.y + a0.z*a0.z + a0.w*a0.w
                 + b0.x*b0.x + b0.y*b0.y + b0.z*b0.z + b0.w*b0.w
                 + a1.x*a1.x + a1.y*a1.y + a1.z*a1.z + a1.w*a1.w
                 + b1.x*b1.x + b1.y*b1.y + b1.z*b1.z + b1.w*b1.w;
        ss += __shfl_xor(ss, 16, 64);
        ss += __shfl_xor(ss, 32, 64);
        diag[r] = ss * DIAG_F;
    }
}

// MFMA core: acc[r][pt] = proj-tile(pt) x data-tile(w*2+r).
// D-layout: data row = lane&15, feature sub-idx = (lane>>4)*4 + reg.
__device__ __forceinline__ void mfma_tiles(const bf16x8 fd[2][2],
                                           unsigned short (*Ps)[2][64][8],
                                           int l, f32x4 acc[2][8]) {
#pragma unroll
    for (int r = 0; r < 2; ++r)
#pragma unroll
        for (int pt = 0; pt < 8; ++pt)
            acc[r][pt] = f32x4{0.f, 0.f, 0.f, 0.f};
#pragma unroll
    for (int pt = 0; pt < 8; ++pt) {
        bf16x8 fp0 = *reinterpret_cast<bf16x8*>(&Ps[pt][0][l][0]);
        bf16x8 fp1 = *reinterpret_cast<bf16x8*>(&Ps[pt][1][l][0]);
#pragma unroll
        for (int r = 0; r < 2; ++r) {
            acc[r][pt] = __builtin_amdgcn_mfma_f32_16x16x32_bf16(fp0, fd[r][0], acc[r][pt], 0, 0, 0);
            acc[r][pt] = __builtin_amdgcn_mfma_f32_16x16x32_bf16(fp1, fd[r][1], acc[r][pt], 0, 0, 0);
        }
    }
}

// ---------------------------------------------------------------------------
// kmax block body: per-block max of (|x| - diag) - HLM -> partials[bid]
// ---------------------------------------------------------------------------
__device__ __forceinline__ void kmax_block(
        int bid, const float* __restrict__ k, const float* __restrict__ proj,
        float* __restrict__ partials, unsigned short (*Ps)[2][64][8],
        float* red, int t) {
    int l = t & 63, w = t >> 6;
    stage_proj(proj, Ps, t);
    bf16x8 fd[2][2];
    float diag[2];
    load_data_frags(k + (size_t)bid * ROWS_PER_BLK * 64, l, w, fd, diag);
    __syncthreads();
    f32x4 acc[2][8];
    mfma_tiles(fd, Ps, l, acc);

    float cand = -INFINITY;
#pragma unroll
    for (int r = 0; r < 2; ++r) {
        float mx = 0.f;
#pragma unroll
        for (int pt = 0; pt < 8; ++pt) {
            f32x4 a = acc[r][pt];
            mx = fmaxf(mx, fmaxf(fmaxf(fabsf(a[0]), fabsf(a[1])),
                                 fmaxf(fabsf(a[2]), fabsf(a[3]))));
        }
        cand = fmaxf(cand, mx - diag[r]);
    }
#pragma unroll
    for (int s = 32; s; s >>= 1) cand = fmaxf(cand, __shfl_xor(cand, s, 64));
    if (l == 0) red[w] = cand;
    __syncthreads();
    if (t == 0)
        partials[bid] = fmaxf(fmaxf(red[0], red[1]), fmaxf(red[2], red[3])) - HLM;
}

// ---------------------------------------------------------------------------
// Feature block body (q or k panel). Full-1KB-row streaming NT stores via
// per-wave LDS bounce with wave-local fences (round-8/9 verified). Proj LDS
// and bounce LDS unioned (disjoint lifetimes, barrier between).
// ---------------------------------------------------------------------------
__device__ __forceinline__ void feat_block(
        bool is_q, int bid,
        const float* __restrict__ data, float* __restrict__ feats,
        float* __restrict__ qls, float* __restrict__ kls,
        const float* __restrict__ partials, const float* __restrict__ proj,
        unsigned char* smem, float* gls_sp, int t) {
    auto Ps = reinterpret_cast<unsigned short(*)[2][64][8]>(smem);
    float* outb = reinterpret_cast<float*>(smem);
    int l = t & 63, w = t >> 6;

    stage_proj(proj, Ps, t);
    bf16x8 fd[2][2];
    float diag[2];
    load_data_frags(data + (size_t)bid * ROWS_PER_BLK * 64, l, w, fd, diag);
    if (!is_q && t < 32) {
        float v = partials[(bid >> 5) * BLKS_PER_BH + t];
#pragma unroll
        for (int s = 16; s; s >>= 1) v = fmaxf(v, __shfl_xor(v, s, 64));
        if (t == 0) *gls_sp = v;
    }
    __syncthreads();
    f32x4 acc[2][8];
    mfma_tiles(fd, Ps, l, acc);

    float gls = 0.f;
    if (!is_q) {
        gls = *gls_sp;
        if ((bid & 31) == 0 && t == 0) kls[bid >> 5] = gls;
    }
    __syncthreads();   // all waves done reading Ps before bounce reuse

    float* ob = outb + w * (8 * OB_STRIDE);
    int myrow = l & 15;         // row within this wave's 16-row tile
    int g = l >> 4;             // 4-feature sub-chunk index

#pragma unroll
    for (int r = 0; r < 2; ++r) {
        float off;
        if (is_q) {
            float mx = 0.f;     // max over concat[x,-x] = max |x|
#pragma unroll
            for (int pt = 0; pt < 8; ++pt) {
                f32x4 a = acc[r][pt];
                mx = fmaxf(mx, fmaxf(fmaxf(fabsf(a[0]), fabsf(a[1])),
                                     fmaxf(fabsf(a[2]), fabsf(a[3]))));
            }
            mx = fmaxf(mx, __shfl_xor(mx, 16, 64));
            mx = fmaxf(mx, __shfl_xor(mx, 32, 64));
            off = mx;
        } else {
            off = diag[r] + HLM + gls;
        }

#pragma unroll
        for (int p = 0; p < 2; ++p) {
            if ((myrow >> 3) == p) {
                float* obr = ob + (myrow & 7) * OB_STRIDE + g * 4;
#pragma unroll
                for (int pt = 0; pt < 8; ++pt) {
                    f32x4 a = acc[r][pt];
                    f32x4 e1, e2;
                    e1[0] = __expf(a[0] - off); e1[1] = __expf(a[1] - off);
                    e1[2] = __expf(a[2] - off); e1[3] = __expf(a[3] - off);
                    e2[0] = __expf(-a[0] - off); e2[1] = __expf(-a[1] - off);
                    e2[2] = __expf(-a[2] - off); e2[3] = __expf(-a[3] - off);
                    *reinterpret_cast<f32x4*>(obr + pt * 16)       = e1;
                    *reinterpret_cast<f32x4*>(obr + pt * 16 + 128) = e2;
                }
            }
            LDS_FENCE();   // fill (cross-lane) visible before drain reads
            size_t Rb = (size_t)bid * ROWS_PER_BLK + (w * 2 + r) * 16 + p * 8;
#pragma unroll
            for (int j = 0; j < 8; ++j) {
                f32x4 v = *reinterpret_cast<f32x4*>(ob + j * OB_STRIDE + l * 4);
                __builtin_nontemporal_store(
                    v, reinterpret_cast<f32x4*>(feats + (Rb + j) * 256 + l * 4));
            }
            LDS_FENCE();   // drain done before next fill overwrites (WAR)
        }
        if (is_q && l < 16) {
            size_t R = (size_t)bid * ROWS_PER_BLK + (w * 2 + r) * 16 + myrow;
            qls[R] = off - diag[r] - HLM;
        }
    }
}

// ---------------------------------------------------------------------------
// Phase 1: kmax (blocks 0..2047) + first half of q features (2048..3071).
// kmax's read-only k stream overlaps the q-half's NT write stream.
// ---------------------------------------------------------------------------
__global__ __launch_bounds__(256, 4) void phase1_kernel(
        const float* __restrict__ q, const float* __restrict__ k,
        const float* __restrict__ proj, float* __restrict__ partials,
        float* __restrict__ qf, float* __restrict__ qls) {
    __shared__ __align__(16) unsigned char smem[4 * 8 * OB_STRIDE * 4];
    __shared__ float gls_s;
    __shared__ float red[4];
    int t = threadIdx.x;
    if (blockIdx.x < NBLOCKS) {
        auto Ps = reinterpret_cast<unsigned short(*)[2][64][8]>(smem);
        kmax_block(blockIdx.x, k, proj, partials, Ps, red, t);
    } else {
        feat_block(true, blockIdx.x - NBLOCKS, q, qf, qls, nullptr,
                   nullptr, proj, smem, &gls_s, t);
    }
}

// ---------------------------------------------------------------------------
// Phase 2: k features (blocks 0..2047; k is L3-hot from phase 1, NT stores
// bypassed the cache) + second half of q features (2048..3071).
// ---------------------------------------------------------------------------
__global__ __launch_bounds__(256, 4) void phase2_kernel(
        const float* __restrict__ q, const float* __restrict__ k,
        const float* __restrict__ proj, const float* __restrict__ partials,
        float* __restrict__ qf, float* __restrict__ qls,
        float* __restrict__ kf, float* __restrict__ kls) {
    __shared__ __align__(16) unsigned char smem[4 * 8 * OB_STRIDE * 4];
    __shared__ float gls_s;
    int t = threadIdx.x;
    if (blockIdx.x < NBLOCKS) {
        feat_block(false, blockIdx.x, k, kf, nullptr, kls,
                   partials, proj, smem, &gls_s, t);
    } else {
        feat_block(true, blockIdx.x - NBLOCKS + QSPLIT, q, qf, qls, nullptr,
                   nullptr, proj, smem, &gls_s, t);
    }
}

extern "C" void kernel_launch(void* const* d_in, const int* in_sizes, int n_in,
                              void* d_out, int out_size, void* d_ws, size_t ws_size,
                              hipStream_t stream) {
    const float* q    = (const float*)d_in[0];
    const float* k    = (const float*)d_in[1];
    const float* proj = (const float*)d_in[2];

    float* out = (float*)d_out;
    float* qf  = out;                                       // (B,H,S,256)
    float* qls = out + (size_t)FEAT_ELEMS;                  // (B,H,S,1)
    float* kf  = out + (size_t)FEAT_ELEMS + ROWS_TOTAL;     // (B,H,S,256)
    float* kls = out + 2 * (size_t)FEAT_ELEMS + ROWS_TOTAL; // (B,H,1,1)

    float* partials = (float*)d_ws;                         // 2048 floats

    phase1_kernel<<<NBLOCKS + QSPLIT, 256, 0, stream>>>(
        q, k, proj, partials, qf, qls);
    phase2_kernel<<<NBLOCKS + (QPANELS - QSPLIT), 256, 0, stream>>>(
        q, k, proj, partials, qf, qls, kf, kls);
}